// Round 11
// baseline (533.219 us; speedup 1.0000x reference)
//
#include <hip/hip_runtime.h>

#define NB 512
#define NPG 256
#define NTOT (NB * NPG)
#define NEGMIN -3.4028234663852886e38f

// padded h row: 68 floats (272 B). Sequential b128 phases are conflict-free;
// random gather sits at its statistical floor. Addressing is 1 VGPR + offset
// immediates (R9 measured: frees ~68 registers vs XOR swizzle -> VGPR 60).
#define HPITCH 68

// workspace layout (float offsets)
#define OFF_WNT 0       // WnT[64][16]   WnT[d][k] = Wn[k][d]
#define OFF_WCT 1024    // WcT[64][64]   WcT[d][k] = Wc[k][d]
#define OFF_W1AT 5120   // W1aT[128][64] W1aT[j][k] = W1[k][j]      (rows 0..63 of W1)
#define OFF_W1BT 13312  // W1bT[128][64] W1bT[j][k] = W1[64+k][j]   (rows 64..127)
#define OFF_BNC 21504   // bn + bc [64]
#define WS_FLOATS 21568

__global__ __launch_bounds__(256) void prep_kernel(
    const float* __restrict__ Wn, const float* __restrict__ bn,
    const float* __restrict__ Wc, const float* __restrict__ bc,
    const float* __restrict__ W1, float* __restrict__ ws)
{
    int i = blockIdx.x * 256 + threadIdx.x;
    if (i < 1024) {
        int d = i >> 4, k = i & 15;
        ws[OFF_WNT + i] = Wn[k * 64 + d];
    } else if (i < 5120) {
        int j = i - 1024; int d = j >> 6, k = j & 63;
        ws[OFF_WCT + j] = Wc[k * 64 + d];
    } else if (i < 13312) {
        int j = i - 5120; int r = j >> 6, k = j & 63;
        ws[OFF_W1AT + j] = W1[k * 128 + r];
    } else if (i < 21504) {
        int j = i - 13312; int r = j >> 6, k = j & 63;
        ws[OFF_W1BT + j] = W1[(64 + k) * 128 + r];
    } else if (i < WS_FLOATS) {
        int d = i - OFF_BNC;
        ws[OFF_BNC + d] = bn[d] + bc[d];
    }
}

// R11 = R10's half-split levels (512 thr/graph, 2 thr/node by dim-half;
// proven bitwise-safe in R3/R4) + R9 padding, with R10's ONE regression
// removed: the MLP raw-sum split (part0+part1+b2[0]) was R1's failing
// order, never proven. MLP here = R4's PROVEN streamed code verbatim:
// full j=0..127 fold from b2[0] under t<256, h streamed from myrow per
// 4-j group (no h[64] reg array).
// Register plan for __launch_bounds__(512,4) -> VGPR 64 (R2/R4-measured),
// enabled by padded addressing (R9: -68 regs vs XOR):
//   gather: own[32]+esp[4] (~40; nf reloaded after, R4's proven trick)
//   update: hnew[32]+nf[16] (~52), pooled streamed from LDS
//   MLP:    ~15 streamed
// -> 16 waves/CU during level phases (2 blocks x 8 waves), zero spill.
// Numerical contract: every phase copied from a kernel that measured
// absmax 82.0 (R0/R3/R4/R9).
__global__ __launch_bounds__(512, 4) void gdqn_kernel(
    const float* __restrict__ nfg, const int* __restrict__ esrcg,
    const int* __restrict__ fmask, const float* __restrict__ ws,
    const float* __restrict__ bn, const float* __restrict__ b1,
    const float* __restrict__ W2, const float* __restrict__ b2,
    float* __restrict__ out)
{
    extern __shared__ float smem[];
    float* hsh  = smem;                     // 256*68 = 17408 (padded rows)
    float* part = smem + 17408;             // 256 (graph-embed partials)
    float* gesh = smem + 17664;             // 64
    float* rpsh = smem + 17728;             // 128
    float* redv = smem + 17856;             // 4
    int*   redi = (int*)(smem + 17860);     // 4
    // total 17864 floats = 71,456 B -> 2 blocks/CU (142,912 <= 163,840)

    const int g = blockIdx.x, t = threadIdx.x;
    const int n = t & 255;                  // node within graph
    const int H = __builtin_amdgcn_readfirstlane(t >> 8);  // wave-uniform half
    const int node = (g << 8) + n;
    float* myrow  = hsh + n * HPITCH;
    const int dbase = H << 5;               // my output dims [dbase, dbase+32)
    float* myhalf = myrow + dbase;          // my 8 chunks start here

    const float* WnT  = ws + OFF_WNT;
    const float* WcT  = ws + OFF_WCT;
    const float* W1aT = ws + OFF_W1AT;
    const float* bnc  = ws + OFF_BNC;

    // neighbor indices packed 4-per-register (values < 256) -> 4 VGPRs
    int esp[4];
    {
        const int4* p = (const int4*)(esrcg + node * 16);
        int4 a = p[0], b = p[1], c = p[2], d = p[3];
        esp[0] = (a.x&255) | ((a.y&255)<<8) | ((a.z&255)<<16) | ((a.w&255)<<24);
        esp[1] = (b.x&255) | ((b.y&255)<<8) | ((b.z&255)<<16) | ((b.w&255)<<24);
        esp[2] = (c.x&255) | ((c.y&255)<<8) | ((c.z&255)<<16) | ((c.w&255)<<24);
        esp[3] = (d.x&255) | ((d.y&255)<<8) | ((d.z&255)<<16) | ((d.w&255)<<24);
    }

    // node features -> regs; h0 = relu(bn-init fold k=0..15) for my 32 dims
    {
        float nf[16];
        const float4* p = (const float4*)(nfg + node * 16);
        float4 a = p[0], b = p[1], c = p[2], d = p[3];
        nf[0]=a.x; nf[1]=a.y; nf[2]=a.z; nf[3]=a.w;
        nf[4]=b.x; nf[5]=b.y; nf[6]=b.z; nf[7]=b.w;
        nf[8]=c.x; nf[9]=c.y; nf[10]=c.z; nf[11]=c.w;
        nf[12]=d.x; nf[13]=d.y; nf[14]=d.z; nf[15]=d.w;
        #pragma unroll
        for (int c2 = 0; c2 < 8; ++c2) {
            float s4[4];
            #pragma unroll
            for (int q = 0; q < 4; ++q) {
                int d2 = dbase + 4 * c2 + q;
                float s = bn[d2];
                #pragma unroll
                for (int k = 0; k < 16; ++k) s = fmaf(nf[k], WnT[d2 * 16 + k], s);
                s4[q] = fmaxf(s, 0.0f);
            }
            ((float4*)myhalf)[c2] = make_float4(s4[0], s4[1], s4[2], s4[3]);
        }
    }
    __syncthreads();

    for (int lv = 0; lv < 3; ++lv) {
        // half-gather: my 8 chunks of 16 neighbor rows, j=0..15 ascending
        // (live: own[32]+esp[4]; nf deliberately NOT live here)
        float own[32];
        #pragma unroll
        for (int i = 0; i < 32; ++i) own[i] = 0.0f;
        #pragma unroll
        for (int j = 0; j < 16; ++j) {
            int s = (esp[j >> 2] >> ((j & 3) * 8)) & 255;
            const float4* rowh = (const float4*)(hsh + s * HPITCH + dbase);
            #pragma unroll
            for (int c = 0; c < 8; ++c) {
                float4 v = rowh[c];         // 1 addr VGPR + offset:16c
                own[4*c+0] += v.x; own[4*c+1] += v.y;
                own[4*c+2] += v.z; own[4*c+3] += v.w;
            }
        }
        // reload nf (values identical to the initial load; latency hides
        // under the barriers) -- R4's proven pressure trick
        float nf[16];
        {
            const float4* p = (const float4*)(nfg + node * 16);
            float4 a = p[0], b = p[1], c = p[2], d = p[3];
            nf[0]=a.x; nf[1]=a.y; nf[2]=a.z; nf[3]=a.w;
            nf[4]=b.x; nf[5]=b.y; nf[6]=b.z; nf[7]=b.w;
            nf[8]=c.x; nf[9]=c.y; nf[10]=c.z; nf[11]=c.w;
            nf[12]=d.x; nf[13]=d.y; nf[14]=d.z; nf[15]=d.w;
        }
        __syncthreads();   // all gather reads of old h done

        // exchange: write my pooled half into my row (natural dim position)
        #pragma unroll
        for (int c = 0; c < 8; ++c)
            ((float4*)myhalf)[c] = make_float4(own[4*c+0], own[4*c+1],
                                               own[4*c+2], own[4*c+3]);
        __syncthreads();   // both halves of pooled[n] visible

        // hnew[d] = bnc[d] -> nf fold k=0..15 -> pooled fold k=0..63 ascending
        // (pooled streamed from LDS; per-output sequence identical to R0;
        // proven passing in R3/R4)
        float hnew[32];
        #pragma unroll
        for (int dq = 0; dq < 32; ++dq) {
            int d = dbase + dq;
            float s = bnc[d];
            #pragma unroll
            for (int k = 0; k < 16; ++k) s = fmaf(nf[k], WnT[d * 16 + k], s);
            hnew[dq] = s;
        }
        #pragma unroll
        for (int kc = 0; kc < 16; ++kc) {
            float4 v = ((const float4*)myrow)[kc];
            int kb = 4 * kc;
            #pragma unroll
            for (int dq = 0; dq < 32; ++dq) {
                const float* wr = WcT + (dbase + dq) * 64;
                float s = hnew[dq];
                s = fmaf(v.x, wr[kb+0], s); s = fmaf(v.y, wr[kb+1], s);
                s = fmaf(v.z, wr[kb+2], s); s = fmaf(v.w, wr[kb+3], s);
                hnew[dq] = s;
            }
        }
        __syncthreads();   // pair finished reading pooled before h overwrite

        #pragma unroll
        for (int c = 0; c < 8; ++c)
            ((float4*)myhalf)[c] =
                make_float4(fmaxf(hnew[4*c+0], 0.0f), fmaxf(hnew[4*c+1], 0.0f),
                            fmaxf(hnew[4*c+2], 0.0f), fmaxf(hnew[4*c+3], 0.0f));
        __syncthreads();
    }

    // graph_embed = relu(column sums of h) -- exact R9 math under t<256
    if (t < 256) {
        int col = t & 63, v0 = (t >> 6) << 6;
        float s = 0.0f;
        for (int v = 0; v < 64; ++v) {
            int vv = v0 + v;
            s += hsh[vv * HPITCH + col];
        }
        part[t] = s;
    }
    __syncthreads();
    if (t < 64) {
        float s = part[t] + part[t + 64] + part[t + 128] + part[t + 192];
        gesh[t] = fmaxf(s, 0.0f);
    }
    __syncthreads();
    // rep_proj[j] = b1[j] + sum_k ge[k] * W1[64+k][j]  (block-uniform MLP half)
    if (t < 128) {
        float s = b1[t];
        const float4* wr = (const float4*)(ws + OFF_W1BT + t * 64);
        #pragma unroll
        for (int c = 0; c < 16; ++c) {
            float4 w = wr[c];
            s = fmaf(gesh[4*c+0], w.x, s);
            s = fmaf(gesh[4*c+1], w.y, s);
            s = fmaf(gesh[4*c+2], w.z, s);
            s = fmaf(gesh[4*c+3], w.w, s);
        }
        rpsh[t] = s;
    }
    __syncthreads();   // rpsh ready

    if (t < 256) {
        // MLP: R4's PROVEN streamed code -- full j=0..127 fold from b2[0],
        // j in groups of 4, per-j k=0..63 ascending via b128 LDS stream.
        // NOT split across thread halves (that was R1/R10's failing order).
        float raw = b2[0];
        for (int jq = 0; jq < 32; ++jq) {   // wave-uniform
            asm volatile("" ::: "memory");  // block LICM from hoisting the row
            int j0 = 4 * jq;
            float z0 = rpsh[j0+0], z1 = rpsh[j0+1];
            float z2 = rpsh[j0+2], z3 = rpsh[j0+3];
            const float* w0 = W1aT + (j0+0) * 64;
            const float* w1 = W1aT + (j0+1) * 64;
            const float* w2 = W1aT + (j0+2) * 64;
            const float* w3 = W1aT + (j0+3) * 64;
            #pragma unroll
            for (int kc = 0; kc < 16; ++kc) {
                float4 v = ((const float4*)myrow)[kc];
                int kb = 4 * kc;
                z0=fmaf(v.x,w0[kb+0],z0); z0=fmaf(v.y,w0[kb+1],z0);
                z0=fmaf(v.z,w0[kb+2],z0); z0=fmaf(v.w,w0[kb+3],z0);
                z1=fmaf(v.x,w1[kb+0],z1); z1=fmaf(v.y,w1[kb+1],z1);
                z1=fmaf(v.z,w1[kb+2],z1); z1=fmaf(v.w,w1[kb+3],z1);
                z2=fmaf(v.x,w2[kb+0],z2); z2=fmaf(v.y,w2[kb+1],z2);
                z2=fmaf(v.z,w2[kb+2],z2); z2=fmaf(v.w,w2[kb+3],z2);
                z3=fmaf(v.x,w3[kb+0],z3); z3=fmaf(v.y,w3[kb+1],z3);
                z3=fmaf(v.z,w3[kb+2],z3); z3=fmaf(v.w,w3[kb+3],z3);
            }
            raw = fmaf(fmaxf(z0, 0.0f), W2[j0+0], raw);
            raw = fmaf(fmaxf(z1, 0.0f), W2[j0+1], raw);
            raw = fmaf(fmaxf(z2, 0.0f), W2[j0+2], raw);
            raw = fmaf(fmaxf(z3, 0.0f), W2[j0+3], raw);
        }
        out[512 + node] = raw;

        // masked max/argmax (first-index tie-break like jnp.argmax)
        float q = fmask[node] ? NEGMIN : raw;
        int idx = t;
        #pragma unroll
        for (int off = 32; off >= 1; off >>= 1) {
            float ov = __shfl_down(q, off, 64);
            int oi  = __shfl_down(idx, off, 64);
            if (ov > q || (ov == q && oi < idx)) { q = ov; idx = oi; }
        }
        if ((t & 63) == 0) { redv[t >> 6] = q; redi[t >> 6] = idx; }
    }
    __syncthreads();
    if (t == 0) {
        float bv = redv[0]; int bi = redi[0];
        #pragma unroll
        for (int w = 1; w < 4; ++w) {
            float v = redv[w]; int iw = redi[w];
            if (v > bv || (v == bv && iw < bi)) { bv = v; bi = iw; }
        }
        out[g] = (float)bi;             // indices (as float)
        out[512 + NTOT + g] = bv;       // values
    }
}

extern "C" void kernel_launch(void* const* d_in, const int* in_sizes, int n_in,
                              void* d_out, int out_size, void* d_ws, size_t ws_size,
                              hipStream_t stream)
{
    const float* nfg   = (const float*)d_in[0];
    const int*   esrc  = (const int*)d_in[1];
    const int*   fmask = (const int*)d_in[4];
    const float* Wn = (const float*)d_in[5];
    const float* bn = (const float*)d_in[6];
    const float* Wc = (const float*)d_in[7];
    const float* bc = (const float*)d_in[8];
    const float* W1 = (const float*)d_in[9];
    const float* b1 = (const float*)d_in[10];
    const float* W2 = (const float*)d_in[11];
    const float* b2 = (const float*)d_in[12];
    float* out = (float*)d_out;
    float* ws  = (float*)d_ws;

    prep_kernel<<<(WS_FLOATS + 255) / 256, 256, 0, stream>>>(Wn, bn, Wc, bc, W1, ws);

    size_t shmem = 17864 * sizeof(float);  // 71,456 B > 64 KB default -> opt in
    static bool s_attr_done = false;
    if (!s_attr_done) {
        hipFuncSetAttribute((const void*)gdqn_kernel,
                            hipFuncAttributeMaxDynamicSharedMemorySize, (int)shmem);
        s_attr_done = true;
    }
    gdqn_kernel<<<NB, 512, shmem, stream>>>(nfg, esrc, fmask, ws, bn, b1, W2, b2, out);
}

// Round 12
// 267.168 us; speedup vs baseline: 1.9958x; 1.9958x over previous
//
#include <hip/hip_runtime.h>

#define NB 512
#define NPG 256
#define NTOT (NB * NPG)
#define NEGMIN -3.4028234663852886e38f

// padded h row: 68 floats (272 B). Sequential b128 phases are conflict-free;
// random gather sits at its statistical floor. Addressing is 1 VGPR + offset
// immediates (R9 measured: VGPR 60, conflicts 1.21e7, zero spill).
#define HPITCH 68

// workspace layout (float offsets)
#define OFF_WNT 0       // WnT[64][16]   WnT[d][k] = Wn[k][d]
#define OFF_WCT 1024    // WcT[64][64]   WcT[d][k] = Wc[k][d]
#define OFF_W1AT 5120   // W1aT[128][64] W1aT[j][k] = W1[k][j]      (rows 0..63 of W1)
#define OFF_W1BT 13312  // W1bT[128][64] W1bT[j][k] = W1[64+k][j]   (rows 64..127)
#define OFF_BNC 21504   // bn + bc [64]
#define WS_FLOATS 21568

__global__ __launch_bounds__(256) void prep_kernel(
    const float* __restrict__ Wn, const float* __restrict__ bn,
    const float* __restrict__ Wc, const float* __restrict__ bc,
    const float* __restrict__ W1, float* __restrict__ ws)
{
    int i = blockIdx.x * 256 + threadIdx.x;
    if (i < 1024) {
        int d = i >> 4, k = i & 15;
        ws[OFF_WNT + i] = Wn[k * 64 + d];
    } else if (i < 5120) {
        int j = i - 1024; int d = j >> 6, k = j & 63;
        ws[OFF_WCT + j] = Wc[k * 64 + d];
    } else if (i < 13312) {
        int j = i - 5120; int r = j >> 6, k = j & 63;
        ws[OFF_W1AT + j] = W1[k * 128 + r];
    } else if (i < 21504) {
        int j = i - 13312; int r = j >> 6, k = j & 63;
        ws[OFF_W1BT + j] = W1[(64 + k) * 128 + r];
    } else if (i < WS_FLOATS) {
        int d = i - OFF_BNC;
        ws[OFF_BNC + d] = bn[d] + bc[d];
    }
}

// R12 = R9 verbatim (the structural optimum: 256 thr/graph, padded rows,
// VGPR 60, spill-free, gather at conflict floor; all five 512-thread
// restructures failed on regalloc) with ONE micro-diff in the MLP:
// j's processed in PAIRS with two independent z-chains. R9's VGPR=60
// proves the compiler streams h from LDS per-j (ILP=1, 4-cyc FMA chain
// latency + ds_read latency, only 2 waves/SIMD to cover). Pairing gives
// ILP 2 x 2 waves = full coverage, and j+1's loads overlap j's FMAs.
// Per-chain k-order (ascending) and the raw j-fold order are unchanged
// -> bitwise identical outputs (absmax 82.0 / threshold 89.6).
__global__ __launch_bounds__(256, 2) void gdqn_kernel(
    const float* __restrict__ nfg, const int* __restrict__ esrcg,
    const int* __restrict__ fmask, const float* __restrict__ ws,
    const float* __restrict__ bn, const float* __restrict__ b1,
    const float* __restrict__ W2, const float* __restrict__ b2,
    float* __restrict__ out)
{
    extern __shared__ float smem[];
    float* hsh  = smem;                     // 256*68 = 17408 (padded rows)
    float* part = smem + 17408;             // 256
    float* gesh = smem + 17664;             // 64
    float* rpsh = smem + 17728;             // 128
    float* redv = smem + 17856;             // 4
    int*   redi = (int*)(smem + 17860);     // 4

    const int g = blockIdx.x, t = threadIdx.x;
    const int node = (g << 8) + t;
    float* myrow = hsh + t * HPITCH;

    const float* WnT  = ws + OFF_WNT;
    const float* WcT  = ws + OFF_WCT;
    const float* W1aT = ws + OFF_W1AT;
    const float* bnc  = ws + OFF_BNC;

    // node features (16 floats) -> regs (always statically indexed)
    float nf[16];
    {
        const float4* p = (const float4*)(nfg + node * 16);
        float4 a = p[0], b = p[1], c = p[2], d = p[3];
        nf[0]=a.x; nf[1]=a.y; nf[2]=a.z; nf[3]=a.w;
        nf[4]=b.x; nf[5]=b.y; nf[6]=b.z; nf[7]=b.w;
        nf[8]=c.x; nf[9]=c.y; nf[10]=c.z; nf[11]=c.w;
        nf[12]=d.x; nf[13]=d.y; nf[14]=d.z; nf[15]=d.w;
    }
    int es[16];
    {
        const int4* p = (const int4*)(esrcg + node * 16);
        int4 a = p[0], b = p[1], c = p[2], d = p[3];
        es[0]=a.x&255; es[1]=a.y&255; es[2]=a.z&255; es[3]=a.w&255;
        es[4]=b.x&255; es[5]=b.y&255; es[6]=b.z&255; es[7]=b.w&255;
        es[8]=c.x&255; es[9]=c.y&255; es[10]=c.z&255; es[11]=c.w&255;
        es[12]=d.x&255; es[13]=d.y&255; es[14]=d.z&255; es[15]=d.w&255;
    }

    // h0 = relu(nf @ Wn + bn) -> straight to LDS (never a reg array)
    for (int c = 0; c < 16; ++c) {          // c is wave-uniform
        float s4[4];
        #pragma unroll
        for (int q = 0; q < 4; ++q) {       // fully unrolled: static indices
            int d = 4 * c + q;
            float s = bn[d];
            #pragma unroll
            for (int k = 0; k < 16; ++k) s = fmaf(nf[k], WnT[d * 16 + k], s);
            s4[q] = fmaxf(s, 0.0f);
        }
        ((float4*)myrow)[c] = make_float4(s4[0], s4[1], s4[2], s4[3]);
    }
    __syncthreads();

    for (int lv = 0; lv < 3; ++lv) {
        // gather-sum 16 neighbor rows from LDS into regs (static indices only)
        float pooled[64];
        #pragma unroll
        for (int k = 0; k < 64; ++k) pooled[k] = 0.0f;
        #pragma unroll
        for (int j = 0; j < 16; ++j) {
            int s = es[j];
            const float4* row = (const float4*)(hsh + s * HPITCH);
            #pragma unroll
            for (int c = 0; c < 16; ++c) {
                float4 v = row[c];          // one addr VGPR + offset:16c
                pooled[4*c+0] += v.x; pooled[4*c+1] += v.y;
                pooled[4*c+2] += v.z; pooled[4*c+3] += v.w;
            }
        }
        __syncthreads();  // all reads of old h done before overwrite

        // h = relu(pooled @ Wc + (bn+bc) + nf@Wn), written directly to LDS
        for (int c = 0; c < 16; ++c) {      // c wave-uniform
            float s4[4];
            #pragma unroll
            for (int q = 0; q < 4; ++q) {
                int d = 4 * c + q;
                float s = bnc[d];
                #pragma unroll
                for (int k = 0; k < 16; ++k) s = fmaf(nf[k], WnT[d * 16 + k], s);
                const float* wr = WcT + d * 64;
                #pragma unroll
                for (int k = 0; k < 64; ++k) s = fmaf(pooled[k], wr[k], s);
                s4[q] = fmaxf(s, 0.0f);
            }
            ((float4*)myrow)[c] = make_float4(s4[0], s4[1], s4[2], s4[3]);
        }
        __syncthreads();
    }

    // graph_embed = relu(sum over nodes of h)  (plain indexing with pad)
    {
        int col = t & 63, v0 = (t >> 6) << 6;
        float s = 0.0f;
        for (int v = 0; v < 64; ++v) {
            int vv = v0 + v;
            s += hsh[vv * HPITCH + col];
        }
        part[t] = s;
    }
    __syncthreads();
    if (t < 64) {
        float s = part[t] + part[t + 64] + part[t + 128] + part[t + 192];
        gesh[t] = fmaxf(s, 0.0f);
    }
    __syncthreads();
    // rep_proj[j] = b1[j] + sum_k ge[k] * W1[64+k][j]  (block-uniform MLP half)
    if (t < 128) {
        float s = b1[t];
        const float4* wr = (const float4*)(ws + OFF_W1BT + t * 64);
        #pragma unroll
        for (int c = 0; c < 16; ++c) {
            float4 w = wr[c];
            s = fmaf(gesh[4*c+0], w.x, s);
            s = fmaf(gesh[4*c+1], w.y, s);
            s = fmaf(gesh[4*c+2], w.z, s);
            s = fmaf(gesh[4*c+3], w.w, s);
        }
        rpsh[t] = s;
    }
    __syncthreads();   // rpsh ready

    // raw_pred = relu([h, rep] @ W1 + b1) @ W2 + b2: j's in PAIRS, two
    // independent z-chains, h streamed from myrow (what the compiler chose
    // anyway at VGPR 60); per-chain k ascending, raw folds j ascending.
    float raw = b2[0];
    for (int jp = 0; jp < 64; ++jp) {       // jp wave-uniform
        int j0 = 2 * jp;
        float z0 = rpsh[j0], z1 = rpsh[j0 + 1];
        const float* w0 = W1aT + j0 * 64;
        const float* w1 = w0 + 64;
        #pragma unroll
        for (int kc = 0; kc < 16; ++kc) {
            float4 v = ((const float4*)myrow)[kc];
            int kb = 4 * kc;
            z0 = fmaf(v.x, w0[kb+0], z0); z1 = fmaf(v.x, w1[kb+0], z1);
            z0 = fmaf(v.y, w0[kb+1], z0); z1 = fmaf(v.y, w1[kb+1], z1);
            z0 = fmaf(v.z, w0[kb+2], z0); z1 = fmaf(v.z, w1[kb+2], z1);
            z0 = fmaf(v.w, w0[kb+3], z0); z1 = fmaf(v.w, w1[kb+3], z1);
        }
        raw = fmaf(fmaxf(z0, 0.0f), W2[j0], raw);
        raw = fmaf(fmaxf(z1, 0.0f), W2[j0 + 1], raw);
    }
    out[512 + node] = raw;

    // masked max/argmax over the graph (first-index tie-break like jnp.argmax)
    float q = fmask[node] ? NEGMIN : raw;
    int idx = t;
    #pragma unroll
    for (int off = 32; off >= 1; off >>= 1) {
        float ov = __shfl_down(q, off, 64);
        int oi  = __shfl_down(idx, off, 64);
        if (ov > q || (ov == q && oi < idx)) { q = ov; idx = oi; }
    }
    if ((t & 63) == 0) { redv[t >> 6] = q; redi[t >> 6] = idx; }
    __syncthreads();
    if (t == 0) {
        float bv = redv[0]; int bi = redi[0];
        #pragma unroll
        for (int w = 1; w < 4; ++w) {
            float v = redv[w]; int iw = redi[w];
            if (v > bv || (v == bv && iw < bi)) { bv = v; bi = iw; }
        }
        out[g] = (float)bi;             // indices (as float)
        out[512 + NTOT + g] = bv;       // values
    }
}

extern "C" void kernel_launch(void* const* d_in, const int* in_sizes, int n_in,
                              void* d_out, int out_size, void* d_ws, size_t ws_size,
                              hipStream_t stream)
{
    const float* nfg   = (const float*)d_in[0];
    const int*   esrc  = (const int*)d_in[1];
    const int*   fmask = (const int*)d_in[4];
    const float* Wn = (const float*)d_in[5];
    const float* bn = (const float*)d_in[6];
    const float* Wc = (const float*)d_in[7];
    const float* bc = (const float*)d_in[8];
    const float* W1 = (const float*)d_in[9];
    const float* b1 = (const float*)d_in[10];
    const float* W2 = (const float*)d_in[11];
    const float* b2 = (const float*)d_in[12];
    float* out = (float*)d_out;
    float* ws  = (float*)d_ws;

    prep_kernel<<<(WS_FLOATS + 255) / 256, 256, 0, stream>>>(Wn, bn, Wc, bc, W1, ws);

    size_t shmem = 17864 * sizeof(float);  // 71,456 B > 64 KB default -> opt in
    static bool s_attr_done = false;
    if (!s_attr_done) {
        hipFuncSetAttribute((const void*)gdqn_kernel,
                            hipFuncAttributeMaxDynamicSharedMemorySize, (int)shmem);
        s_attr_done = true;
    }
    gdqn_kernel<<<NB, 256, shmem, stream>>>(nfg, esrc, fmask, ws, bn, b1, W2, b2, out);
}

// Round 13
// 261.441 us; speedup vs baseline: 2.0395x; 1.0219x over previous
//
#include <hip/hip_runtime.h>

#define NB 512
#define NPG 256
#define NTOT (NB * NPG)
#define NEGMIN -3.4028234663852886e38f

// padded h row: 68 floats (272 B). Sequential b128 phases are conflict-free
// (+16B-per-row pad); random gather sits at its statistical floor. Addressing
// is 1 VGPR + offset immediates (R9 measured: VGPR 60, conflicts 1.21e7,
// zero spill, gdqn 178 us -- the session optimum).
#define HPITCH 68

// workspace layout (float offsets)
#define OFF_WNT 0       // WnT[64][16]   WnT[d][k] = Wn[k][d]
#define OFF_WCT 1024    // WcT[64][64]   WcT[d][k] = Wc[k][d]
#define OFF_W1AT 5120   // W1aT[128][64] W1aT[j][k] = W1[k][j]      (rows 0..63 of W1)
#define OFF_W1BT 13312  // W1bT[128][64] W1bT[j][k] = W1[64+k][j]   (rows 64..127)
#define OFF_BNC 21504   // bn + bc [64]
#define WS_FLOATS 21568

__global__ __launch_bounds__(256) void prep_kernel(
    const float* __restrict__ Wn, const float* __restrict__ bn,
    const float* __restrict__ Wc, const float* __restrict__ bc,
    const float* __restrict__ W1, float* __restrict__ ws)
{
    int i = blockIdx.x * 256 + threadIdx.x;
    if (i < 1024) {
        int d = i >> 4, k = i & 15;
        ws[OFF_WNT + i] = Wn[k * 64 + d];
    } else if (i < 5120) {
        int j = i - 1024; int d = j >> 6, k = j & 63;
        ws[OFF_WCT + j] = Wc[k * 64 + d];
    } else if (i < 13312) {
        int j = i - 5120; int r = j >> 6, k = j & 63;
        ws[OFF_W1AT + j] = W1[k * 128 + r];
    } else if (i < 21504) {
        int j = i - 13312; int r = j >> 6, k = j & 63;
        ws[OFF_W1BT + j] = W1[(64 + k) * 128 + r];
    } else if (i < WS_FLOATS) {
        int d = i - OFF_BNC;
        ws[OFF_BNC + d] = bn[d] + bc[d];
    }
}

// FINAL = R9 verbatim, the measured optimum of every axis explored this
// session (12 rounds):
//  - 256 threads/graph (five 512-thread variants all spill or halve waves)
//  - padded rows, not XOR swizzle (VGPR 128->60, conflicts 1.92e7->1.21e7)
//  - MLP single z-chain (ILP-2 = +10 us R12; ILP-4 and unroll-2 = spill)
// Occupancy is LDS-locked at 8 waves/CU (hsh = 256x68x4 B fp32, irreducible
// given the 82.0/89.6 absmax margin). Outputs bitwise-identical to the
// round-0 baseline (absmax 82.0).
__global__ __launch_bounds__(256, 2) void gdqn_kernel(
    const float* __restrict__ nfg, const int* __restrict__ esrcg,
    const int* __restrict__ fmask, const float* __restrict__ ws,
    const float* __restrict__ bn, const float* __restrict__ b1,
    const float* __restrict__ W2, const float* __restrict__ b2,
    float* __restrict__ out)
{
    extern __shared__ float smem[];
    float* hsh  = smem;                     // 256*68 = 17408 (padded rows)
    float* part = smem + 17408;             // 256
    float* gesh = smem + 17664;             // 64
    float* rpsh = smem + 17728;             // 128
    float* redv = smem + 17856;             // 4
    int*   redi = (int*)(smem + 17860);     // 4

    const int g = blockIdx.x, t = threadIdx.x;
    const int node = (g << 8) + t;
    float* myrow = hsh + t * HPITCH;

    const float* WnT  = ws + OFF_WNT;
    const float* WcT  = ws + OFF_WCT;
    const float* W1aT = ws + OFF_W1AT;
    const float* bnc  = ws + OFF_BNC;

    // node features (16 floats) -> regs (always statically indexed)
    float nf[16];
    {
        const float4* p = (const float4*)(nfg + node * 16);
        float4 a = p[0], b = p[1], c = p[2], d = p[3];
        nf[0]=a.x; nf[1]=a.y; nf[2]=a.z; nf[3]=a.w;
        nf[4]=b.x; nf[5]=b.y; nf[6]=b.z; nf[7]=b.w;
        nf[8]=c.x; nf[9]=c.y; nf[10]=c.z; nf[11]=c.w;
        nf[12]=d.x; nf[13]=d.y; nf[14]=d.z; nf[15]=d.w;
    }
    int es[16];
    {
        const int4* p = (const int4*)(esrcg + node * 16);
        int4 a = p[0], b = p[1], c = p[2], d = p[3];
        es[0]=a.x&255; es[1]=a.y&255; es[2]=a.z&255; es[3]=a.w&255;
        es[4]=b.x&255; es[5]=b.y&255; es[6]=b.z&255; es[7]=b.w&255;
        es[8]=c.x&255; es[9]=c.y&255; es[10]=c.z&255; es[11]=c.w&255;
        es[12]=d.x&255; es[13]=d.y&255; es[14]=d.z&255; es[15]=d.w&255;
    }

    // h0 = relu(nf @ Wn + bn) -> straight to LDS (never a reg array)
    for (int c = 0; c < 16; ++c) {          // c is wave-uniform
        float s4[4];
        #pragma unroll
        for (int q = 0; q < 4; ++q) {       // fully unrolled: static indices
            int d = 4 * c + q;
            float s = bn[d];
            #pragma unroll
            for (int k = 0; k < 16; ++k) s = fmaf(nf[k], WnT[d * 16 + k], s);
            s4[q] = fmaxf(s, 0.0f);
        }
        ((float4*)myrow)[c] = make_float4(s4[0], s4[1], s4[2], s4[3]);
    }
    __syncthreads();

    for (int lv = 0; lv < 3; ++lv) {
        // gather-sum 16 neighbor rows from LDS into regs (static indices only)
        float pooled[64];
        #pragma unroll
        for (int k = 0; k < 64; ++k) pooled[k] = 0.0f;
        #pragma unroll
        for (int j = 0; j < 16; ++j) {
            int s = es[j];
            const float4* row = (const float4*)(hsh + s * HPITCH);
            #pragma unroll
            for (int c = 0; c < 16; ++c) {
                float4 v = row[c];          // one addr VGPR + offset:16c
                pooled[4*c+0] += v.x; pooled[4*c+1] += v.y;
                pooled[4*c+2] += v.z; pooled[4*c+3] += v.w;
            }
        }
        __syncthreads();  // all reads of old h done before overwrite

        // h = relu(pooled @ Wc + (bn+bc) + nf@Wn), written directly to LDS
        for (int c = 0; c < 16; ++c) {      // c wave-uniform
            float s4[4];
            #pragma unroll
            for (int q = 0; q < 4; ++q) {
                int d = 4 * c + q;
                float s = bnc[d];
                #pragma unroll
                for (int k = 0; k < 16; ++k) s = fmaf(nf[k], WnT[d * 16 + k], s);
                const float* wr = WcT + d * 64;
                #pragma unroll
                for (int k = 0; k < 64; ++k) s = fmaf(pooled[k], wr[k], s);
                s4[q] = fmaxf(s, 0.0f);
            }
            ((float4*)myrow)[c] = make_float4(s4[0], s4[1], s4[2], s4[3]);
        }
        __syncthreads();
    }

    // graph_embed = relu(sum over nodes of h)  (plain indexing with pad)
    {
        int col = t & 63, v0 = (t >> 6) << 6;
        float s = 0.0f;
        for (int v = 0; v < 64; ++v) {
            int vv = v0 + v;
            s += hsh[vv * HPITCH + col];
        }
        part[t] = s;
    }
    __syncthreads();
    if (t < 64) {
        float s = part[t] + part[t + 64] + part[t + 128] + part[t + 192];
        gesh[t] = fmaxf(s, 0.0f);
    }
    __syncthreads();
    // rep_proj[j] = b1[j] + sum_k ge[k] * W1[64+k][j]  (block-uniform MLP half)
    if (t < 128) {
        float s = b1[t];
        const float4* wr = (const float4*)(ws + OFF_W1BT + t * 64);
        #pragma unroll
        for (int c = 0; c < 16; ++c) {
            float4 w = wr[c];
            s = fmaf(gesh[4*c+0], w.x, s);
            s = fmaf(gesh[4*c+1], w.y, s);
            s = fmaf(gesh[4*c+2], w.z, s);
            s = fmaf(gesh[4*c+3], w.w, s);
        }
        rpsh[t] = s;
    }

    // reload this node's h from LDS into regs (static chunk unroll; pooled/es
    // are dead here so the live set is small)
    float h[64];
    #pragma unroll
    for (int c = 0; c < 16; ++c) {
        float4 v = ((const float4*)myrow)[c];
        h[4*c+0] = v.x; h[4*c+1] = v.y; h[4*c+2] = v.z; h[4*c+3] = v.w;
    }
    __syncthreads();

    // raw_pred = relu([h, rep] @ W1 + b1) @ W2 + b2  (per-node half only)
    float raw = b2[0];
    for (int j = 0; j < 128; ++j) {         // j wave-uniform; h[k] static
        float z = rpsh[j];
        const float* wr = W1aT + j * 64;
        #pragma unroll
        for (int k = 0; k < 64; ++k) z = fmaf(h[k], wr[k], z);
        raw = fmaf(fmaxf(z, 0.0f), W2[j], raw);
    }
    out[512 + node] = raw;

    // masked max/argmax over the graph (first-index tie-break like jnp.argmax)
    float q = fmask[node] ? NEGMIN : raw;
    int idx = t;
    #pragma unroll
    for (int off = 32; off >= 1; off >>= 1) {
        float ov = __shfl_down(q, off, 64);
        int oi  = __shfl_down(idx, off, 64);
        if (ov > q || (ov == q && oi < idx)) { q = ov; idx = oi; }
    }
    if ((t & 63) == 0) { redv[t >> 6] = q; redi[t >> 6] = idx; }
    __syncthreads();
    if (t == 0) {
        float bv = redv[0]; int bi = redi[0];
        #pragma unroll
        for (int w = 1; w < 4; ++w) {
            float v = redv[w]; int iw = redi[w];
            if (v > bv || (v == bv && iw < bi)) { bv = v; bi = iw; }
        }
        out[g] = (float)bi;             // indices (as float)
        out[512 + NTOT + g] = bv;       // values
    }
}

extern "C" void kernel_launch(void* const* d_in, const int* in_sizes, int n_in,
                              void* d_out, int out_size, void* d_ws, size_t ws_size,
                              hipStream_t stream)
{
    const float* nfg   = (const float*)d_in[0];
    const int*   esrc  = (const int*)d_in[1];
    const int*   fmask = (const int*)d_in[4];
    const float* Wn = (const float*)d_in[5];
    const float* bn = (const float*)d_in[6];
    const float* Wc = (const float*)d_in[7];
    const float* bc = (const float*)d_in[8];
    const float* W1 = (const float*)d_in[9];
    const float* b1 = (const float*)d_in[10];
    const float* W2 = (const float*)d_in[11];
    const float* b2 = (const float*)d_in[12];
    float* out = (float*)d_out;
    float* ws  = (float*)d_ws;

    prep_kernel<<<(WS_FLOATS + 255) / 256, 256, 0, stream>>>(Wn, bn, Wc, bc, W1, ws);

    size_t shmem = 17864 * sizeof(float);  // 71,456 B > 64 KB default -> opt in
    static bool s_attr_done = false;
    if (!s_attr_done) {
        hipFuncSetAttribute((const void*)gdqn_kernel,
                            hipFuncAttributeMaxDynamicSharedMemorySize, (int)shmem);
        s_attr_done = true;
    }
    gdqn_kernel<<<NB, 256, shmem, stream>>>(nfg, esrc, fmask, ws, bn, b1, W2, b2, out);
}